// Round 17
// baseline (64.024 us; speedup 1.0000x reference)
//
#include <hip/hip_runtime.h>

// n=4, L=8192, h=8, e=64, fp32 in/out
#define N_      4
#define L_      8192
#define H_      8
#define E_      64
#define NH_     (N_ * H_)
#define STRIDE_ (H_ * E_)          // 512 floats between rows
#define CHR_    64                 // rows per staged chunk (swizzle needs 64)
#define SPLIT_  16                 // r16-proven best split
#define RPB_    (L_ / SPLIT_)      // 512 rows per block
#define NCHK_   (RPB_ / CHR_)      // 8 chunk iterations

typedef short bf16x8 __attribute__((ext_vector_type(8)));
typedef float f32x16 __attribute__((ext_vector_type(16)));

__device__ __forceinline__ float featmap(float x) {
    float xs = x * 0.35355339059327373f;   // * 64^-0.25
    return xs > 0.0f ? xs + 1.0f : __expf(xs);
}
__device__ __forceinline__ unsigned short f2bf(float f) {   // RNE f32->bf16
    union { float f; unsigned u; } c{f};
    unsigned r = c.u + 0x7FFFu + ((c.u >> 16) & 1u);
    return (unsigned short)(r >> 16);
}
__device__ __forceinline__ unsigned cvt_pk_bf16(float lo, float hi) {
    unsigned r;
    asm("v_cvt_pk_bf16_f32 %0, %1, %2" : "=v"(r) : "v"(lo), "v"(hi));
    return r;
}
__device__ __forceinline__ int swz_slot(int d, int sp4) {   // sp4 = sp>>2
    return (sp4 ^ (d & 7) ^ ((d >> 2) & 7)) & 7;
}

// ---------------------------------------------------------------------------
// Phase 1 (r16 structure + DEPTH-2 register prefetch).
// r16's la_kv had MLP duty cycle ~30%: 8 loads/thread issued once per chunk,
// zero outstanding the rest of the chunk. Depth-2: two register buffer sets
// (compile-time indexed under full unroll), prologue issues chunks 0,1;
// iter ch: STORE(buf=ch&1) -> barrier -> re-issue that set for ch+2 ->
// COMPUTE. Loads get 2 chunk-periods to return; 8-16 float4/thread stay
// outstanding continuously. LDS dbuf safety: identical two-barrier argument
// as r8/r12 (a wave at STORE(ch+2) has passed barrier(ch+1), so every wave
// finished COMPUTE(ch)). Swizzle/compute/ksum byte-identical to r16.
// ---------------------------------------------------------------------------
__global__ __launch_bounds__(256) void la_kv(
    const float* __restrict__ keys, const float* __restrict__ values,
    float* __restrict__ pkv, float* __restrict__ pks)
{
    const int blk = blockIdx.x;
    const int nh = blk / SPLIT_, chunk = blk % SPLIT_;
    const int n = nh / H_, h = nh % H_;
    const int t = threadIdx.x, l = t & 63;
    const int w = t >> 6, wd = w >> 1, wm = w & 1;
    const int lm = l & 31, lh = l >> 5;
    const int pr = t >> 3, c = t & 7;      // row-pair 0..31, col-octet 0..7

    __shared__ unsigned Kb[2][CHR_][32];   // [buf][d][swizzled s-pair] 16 KB
    __shared__ unsigned Vb[2][CHR_][32];   // 16 KB

    f32x16 acc = {0,0,0,0,0,0,0,0,0,0,0,0,0,0,0,0};
    float ksp[8] = {0.f,0.f,0.f,0.f,0.f,0.f,0.f,0.f};

    const size_t base = (size_t)n * (L_ * H_ * E_) + (size_t)h * E_;
    const size_t rbase = base + (size_t)(chunk * RPB_ + 2 * pr) * STRIDE_ + 4 * c;

    float4 kr[2][4], vr[2][4];             // two buffer sets (64 VGPR)

#define LOADCH(CH, B) {                                                       \
    const size_t nb = rbase + (size_t)(CH) * CHR_ * STRIDE_;                  \
    kr[B][0] = *(const float4*)(keys + nb);                                   \
    kr[B][1] = *(const float4*)(keys + nb + 32);                              \
    kr[B][2] = *(const float4*)(keys + nb + STRIDE_);                         \
    kr[B][3] = *(const float4*)(keys + nb + STRIDE_ + 32);                    \
    vr[B][0] = *(const float4*)(values + nb);                                 \
    vr[B][1] = *(const float4*)(values + nb + 32);                            \
    vr[B][2] = *(const float4*)(values + nb + STRIDE_);                       \
    vr[B][3] = *(const float4*)(values + nb + STRIDE_ + 32); }

    LOADCH(0, 0);
    LOADCH(1, 1);

    #pragma unroll
    for (int ch = 0; ch < NCHK_; ++ch) {
        const int buf = ch & 1;            // compile-time under full unroll
        float a0[4] = {kr[buf][0].x, kr[buf][0].y, kr[buf][0].z, kr[buf][0].w};
        float a1[4] = {kr[buf][1].x, kr[buf][1].y, kr[buf][1].z, kr[buf][1].w};
        float a2[4] = {kr[buf][2].x, kr[buf][2].y, kr[buf][2].z, kr[buf][2].w};
        float a3[4] = {kr[buf][3].x, kr[buf][3].y, kr[buf][3].z, kr[buf][3].w};
        float b0[4] = {vr[buf][0].x, vr[buf][0].y, vr[buf][0].z, vr[buf][0].w};
        float b1[4] = {vr[buf][1].x, vr[buf][1].y, vr[buf][1].z, vr[buf][1].w};
        float b2[4] = {vr[buf][2].x, vr[buf][2].y, vr[buf][2].z, vr[buf][2].w};
        float b3[4] = {vr[buf][3].x, vr[buf][3].y, vr[buf][3].z, vr[buf][3].w};

        #pragma unroll
        for (int i = 0; i < 4; ++i) {
            const float f0 = featmap(a0[i]), f1 = featmap(a1[i]);
            const float f2 = featmap(a2[i]), f3 = featmap(a3[i]);
            ksp[i]     += f0 + f2;
            ksp[4 + i] += f1 + f3;
            const int dl = 4 * c + i, dh = 32 + 4 * c + i;
            const int wl = swz_slot(dl, pr >> 2) * 4 + (pr & 3);
            const int wh = swz_slot(dh, pr >> 2) * 4 + (pr & 3);
            Kb[buf][dl][wl] = cvt_pk_bf16(f0, f2);      // lo = even s
            Kb[buf][dh][wh] = cvt_pk_bf16(f1, f3);
            Vb[buf][dl][wl] = cvt_pk_bf16(b0[i], b2[i]);
            Vb[buf][dh][wh] = cvt_pk_bf16(b1[i], b3[i]);
        }

        __syncthreads();

        if (ch + 2 < NCHK_) LOADCH(ch + 2, buf);   // re-issue freed set

        const int rk = 32 * wd + lm, rv = 32 * wm + lm;
        #pragma unroll
        for (int m = 0; m < 4; ++m) {
            const int sa = ((2 * m + lh) ^ (lm & 7) ^ (lm >> 2)) & 7;
            bf16x8 af = *(const bf16x8*)&Kb[buf][rk][sa * 4];
            bf16x8 bv = *(const bf16x8*)&Vb[buf][rv][sa * 4];
            acc = __builtin_amdgcn_mfma_f32_32x32x16_bf16(af, bv, acc, 0, 0, 0);
        }
    }
#undef LOADCH

    // C/D layout (m74/m101): col=lane&31, row=(r&3)+8*(r>>2)+4*(lane>>5)
    float* dst = pkv + (size_t)blk * (E_ * E_);
    #pragma unroll
    for (int r = 0; r < 16; ++r) {
        const int ro = (r & 3) + 8 * (r >> 2) + 4 * lh;
        dst[(32 * wd + ro) * E_ + 32 * wm + lm] = acc[r];
    }

    // ksum: per-thread partials [8] -> LDS scratch (reuse Kb[0]) -> reduce
    __syncthreads();
    float* ksb = (float*)&Kb[0][0][0];     // [256][8] f32 = 8 KB
    *(float4*)&ksb[t * 8]     = make_float4(ksp[0], ksp[1], ksp[2], ksp[3]);
    *(float4*)&ksb[t * 8 + 4] = make_float4(ksp[4], ksp[5], ksp[6], ksp[7]);
    __syncthreads();
    if (t < E_) {
        const int cc = (t & 31) >> 2, e = (t >> 5) * 4 + (t & 3);
        float s = 0.f;
        #pragma unroll
        for (int pp = 0; pp < 32; ++pp) s += ksb[(pp * 8 + cc) * 8 + e];
        pks[(size_t)blk * E_ + t] = s;
    }
}

// ---------------------------------------------------------------------------
// Reduce: KV[d][m] = sum_c pkv; emit KV^T bf16 [m][d] + ksum f32.
// ---------------------------------------------------------------------------
__global__ __launch_bounds__(256) void la_reduce(
    const float* __restrict__ pkv, const float* __restrict__ pks,
    unsigned short* __restrict__ kvt, float* __restrict__ ksum)
{
    const int b = blockIdx.x, nh = b >> 4, sl = b & 15;
    const int e = sl * 256 + threadIdx.x;          // e = d*64 + m
    const float* src = pkv + (size_t)nh * SPLIT_ * (E_ * E_) + e;
    float s = 0.f;
    #pragma unroll
    for (int c = 0; c < SPLIT_; ++c) s += src[(size_t)c * (E_ * E_)];
    const int d = e >> 6, m = e & 63;
    kvt[(size_t)nh * (E_ * E_) + m * E_ + d] = f2bf(s);

    if (sl == 0 && threadIdx.x < E_) {
        const float* sp = pks + (size_t)nh * SPLIT_ * E_ + threadIdx.x;
        float ss = 0.f;
        #pragma unroll
        for (int c = 0; c < SPLIT_; ++c) ss += sp[c * E_];
        ksum[nh * E_ + threadIdx.x] = ss;
    }
}

// ---------------------------------------------------------------------------
// Phase 2: out[l][m] = z[l] * sum_d qf[l,d]*KV[d,m] via MFMA (r16 verbatim).
// ---------------------------------------------------------------------------
__global__ __launch_bounds__(256) void la_out(
    const float* __restrict__ q, const unsigned short* __restrict__ kvt,
    const float* __restrict__ ksum, float* __restrict__ out)
{
    const int blk = blockIdx.x, nh = blk >> 5, tile = blk & 31;
    const int n = nh / H_, h = nh % H_;
    const int t = threadIdx.x, l = t & 63, w = t >> 6;
    const int lm = l & 31, lh = l >> 5;

    __shared__ float zbuf[4][32];

    const unsigned short* kb = kvt + (size_t)nh * (E_ * E_);
    const float* ks = ksum + nh * E_;

    bf16x8 bfr[4][2];
    float4 kr[4][2];
    #pragma unroll
    for (int st = 0; st < 4; ++st) {
        #pragma unroll
        for (int c = 0; c < 2; ++c)
            bfr[st][c] = *(const bf16x8*)&kb[(32 * c + lm) * E_ + st * 16 + 8 * lh];
        kr[st][0] = *(const float4*)&ks[st * 16 + 8 * lh];
        kr[st][1] = *(const float4*)&ks[st * 16 + 8 * lh + 4];
    }

    const size_t base = (size_t)n * (L_ * H_ * E_) + (size_t)h * E_;

    #pragma unroll
    for (int bnd = 0; bnd < 2; ++bnd) {
        const int l0 = tile * 256 + w * 64 + bnd * 32;
        const float* qp = q + base + (size_t)(l0 + lm) * STRIDE_ + 8 * lh;

        float4 qa[4], qb[4];
        #pragma unroll
        for (int st = 0; st < 4; ++st) {
            qa[st] = *(const float4*)(qp + st * 16);
            qb[st] = *(const float4*)(qp + st * 16 + 4);
        }

        float zd = 0.f;
        bf16x8 af[4];
        #pragma unroll
        for (int st = 0; st < 4; ++st) {
            const float f0 = featmap(qa[st].x), f1 = featmap(qa[st].y),
                        f2 = featmap(qa[st].z), f3 = featmap(qa[st].w);
            const float g0 = featmap(qb[st].x), g1 = featmap(qb[st].y),
                        g2 = featmap(qb[st].z), g3 = featmap(qb[st].w);
            zd += f0 * kr[st][0].x + f1 * kr[st][0].y + f2 * kr[st][0].z + f3 * kr[st][0].w
                + g0 * kr[st][1].x + g1 * kr[st][1].y + g2 * kr[st][1].z + g3 * kr[st][1].w;
            union { bf16x8 v; unsigned u[4]; } a;
            a.u[0] = cvt_pk_bf16(f0, f1);
            a.u[1] = cvt_pk_bf16(f2, f3);
            a.u[2] = cvt_pk_bf16(g0, g1);
            a.u[3] = cvt_pk_bf16(g2, g3);
            af[st] = a.v;
        }
        zd += __shfl_xor(zd, 32);
        const float z = 1.0f / (zd + 1e-6f);
        if (l < 32) zbuf[w][l] = z;
        __builtin_amdgcn_wave_barrier();

        f32x16 c0 = {0,0,0,0,0,0,0,0,0,0,0,0,0,0,0,0};
        f32x16 c1 = {0,0,0,0,0,0,0,0,0,0,0,0,0,0,0,0};
        #pragma unroll
        for (int st = 0; st < 4; ++st) {
            c0 = __builtin_amdgcn_mfma_f32_32x32x16_bf16(af[st], bfr[st][0], c0, 0, 0, 0);
            c1 = __builtin_amdgcn_mfma_f32_32x32x16_bf16(af[st], bfr[st][1], c1, 0, 0, 0);
        }

        float* op = out + base + (size_t)l0 * STRIDE_ + lm;
        #pragma unroll
        for (int r = 0; r < 16; ++r) {
            const int ro = (r & 3) + 8 * (r >> 2) + 4 * lh;
            const float zz = zbuf[w][ro];
            op[(size_t)ro * STRIDE_]      = c0[r] * zz;
            op[(size_t)ro * STRIDE_ + 32] = c1[r] * zz;
        }
        __builtin_amdgcn_wave_barrier();   // zbuf reused next band
    }
}

// ws layout (floats): pkv[NH*SPLIT][4096] | pks[NH*SPLIT][64] |
//                     kvt bf16 (float-sized area) | ksum[NH][64]
extern "C" void kernel_launch(void* const* d_in, const int* in_sizes, int n_in,
                              void* d_out, int out_size, void* d_ws, size_t ws_size,
                              hipStream_t stream) {
    (void)in_sizes; (void)n_in; (void)out_size; (void)ws_size;
    const float* qq = (const float*)d_in[0];
    const float* kk = (const float*)d_in[1];
    const float* vv = (const float*)d_in[2];
    float* outp = (float*)d_out;
    float* ws   = (float*)d_ws;

    float* pkv = ws;
    float* pks = ws + (size_t)NH_ * SPLIT_ * (E_ * E_);
    unsigned short* kvt = (unsigned short*)(pks + (size_t)NH_ * SPLIT_ * E_);
    float* ksm = (float*)(kvt + (size_t)NH_ * (E_ * E_));

    la_kv<<<NH_ * SPLIT_, 256, 0, stream>>>(kk, vv, pkv, pks);
    la_reduce<<<NH_ * 16, 256, 0, stream>>>(pkv, pks, kvt, ksm);
    la_out<<<NH_ * 32, 256, 0, stream>>>(qq, kvt, ksm, outp);
}

// Round 18
// 63.263 us; speedup vs baseline: 1.0120x; 1.0120x over previous
//
#include <hip/hip_runtime.h>

// n=4, L=8192, h=8, e=64, fp32 in/out
#define N_      4
#define L_      8192
#define H_      8
#define E_      64
#define NH_     (N_ * H_)
#define STRIDE_ (H_ * E_)          // 512 floats between rows
#define CHR_    64                 // rows per staged chunk (swizzle needs 64)
#define SPLIT_  16                 // best measured split (r16)
#define RPB_    (L_ / SPLIT_)      // 512 rows per block
#define NCHK_   (RPB_ / CHR_)      // 8 chunk iterations

typedef short bf16x8 __attribute__((ext_vector_type(8)));
typedef float f32x16 __attribute__((ext_vector_type(16)));

__device__ __forceinline__ float featmap(float x) {
    float xs = x * 0.35355339059327373f;   // * 64^-0.25
    return xs > 0.0f ? xs + 1.0f : __expf(xs);
}
__device__ __forceinline__ unsigned short f2bf(float f) {   // RNE f32->bf16
    union { float f; unsigned u; } c{f};
    unsigned r = c.u + 0x7FFFu + ((c.u >> 16) & 1u);
    return (unsigned short)(r >> 16);
}
__device__ __forceinline__ unsigned cvt_pk_bf16(float lo, float hi) {
    unsigned r;
    asm("v_cvt_pk_bf16_f32 %0, %1, %2" : "=v"(r) : "v"(lo), "v"(hi));
    return r;
}
__device__ __forceinline__ int swz_slot(int d, int sp4) {   // sp4 = sp>>2
    return (sp4 ^ (d & 7) ^ ((d >> 2) & 7)) & 7;
}

// ---------------------------------------------------------------------------
// Phase 1 (r16 verbatim -- best measured config, 62.8 us total).
// KV_partial[d][m] = sum_s kf[s,d]*v[s,m] via bf16 MFMA 32x32x16.
// 512 blocks x 8 chunks: long pipelines amortize the latency prologue,
// pkv partial traffic minimized (8.4 MB). Depth-1 prefetch (depth-2 was
// neutral-to-negative, r17). Swizzle r8-proven; one barrier per chunk.
// Perf ceiling analysis (r14 probes + r16/r17 counters): per replay the
// combined working set q+out+k+v = 268 MB > 256 MB L3, so la_kv misses
// ~half its reads to HBM (FETCH = 65.6 MB/replay) as 256-B h-slice
// granules at 2 KB stride; at small-granule HBM efficiency that is
// ~30-35 us -- matching la_kv's real ~39 us. la_out runs at the HBM
// roofline (134 MB @ ~6.4 TB/s = 21 us). Structure-invariant across 8
// la_kv rebuilds (r4-r17).
// ---------------------------------------------------------------------------
__global__ __launch_bounds__(256) void la_kv(
    const float* __restrict__ keys, const float* __restrict__ values,
    float* __restrict__ pkv, float* __restrict__ pks)
{
    const int blk = blockIdx.x;
    const int nh = blk / SPLIT_, chunk = blk % SPLIT_;
    const int n = nh / H_, h = nh % H_;
    const int t = threadIdx.x, l = t & 63;
    const int w = t >> 6, wd = w >> 1, wm = w & 1;
    const int lm = l & 31, lh = l >> 5;
    const int pr = t >> 3, c = t & 7;      // row-pair 0..31, col-octet 0..7

    __shared__ unsigned Kb[2][CHR_][32];   // [buf][d][swizzled s-pair] 16 KB
    __shared__ unsigned Vb[2][CHR_][32];   // 16 KB

    f32x16 acc = {0,0,0,0,0,0,0,0,0,0,0,0,0,0,0,0};
    float ksp[8] = {0.f,0.f,0.f,0.f,0.f,0.f,0.f,0.f};

    const size_t base = (size_t)n * (L_ * H_ * E_) + (size_t)h * E_;
    const size_t rbase = base + (size_t)(chunk * RPB_ + 2 * pr) * STRIDE_ + 4 * c;

    float4 kr0 = *(const float4*)(keys + rbase);
    float4 kr1 = *(const float4*)(keys + rbase + 32);
    float4 kr2 = *(const float4*)(keys + rbase + STRIDE_);
    float4 kr3 = *(const float4*)(keys + rbase + STRIDE_ + 32);
    float4 vr0 = *(const float4*)(values + rbase);
    float4 vr1 = *(const float4*)(values + rbase + 32);
    float4 vr2 = *(const float4*)(values + rbase + STRIDE_);
    float4 vr3 = *(const float4*)(values + rbase + STRIDE_ + 32);

    #pragma unroll
    for (int ch = 0; ch < NCHK_; ++ch) {
        const int buf = ch & 1;
        float a0[4] = {kr0.x, kr0.y, kr0.z, kr0.w};
        float a1[4] = {kr1.x, kr1.y, kr1.z, kr1.w};
        float a2[4] = {kr2.x, kr2.y, kr2.z, kr2.w};
        float a3[4] = {kr3.x, kr3.y, kr3.z, kr3.w};
        float b0[4] = {vr0.x, vr0.y, vr0.z, vr0.w};
        float b1[4] = {vr1.x, vr1.y, vr1.z, vr1.w};
        float b2[4] = {vr2.x, vr2.y, vr2.z, vr2.w};
        float b3[4] = {vr3.x, vr3.y, vr3.z, vr3.w};

        #pragma unroll
        for (int i = 0; i < 4; ++i) {
            const float f0 = featmap(a0[i]), f1 = featmap(a1[i]);
            const float f2 = featmap(a2[i]), f3 = featmap(a3[i]);
            ksp[i]     += f0 + f2;
            ksp[4 + i] += f1 + f3;
            const int dl = 4 * c + i, dh = 32 + 4 * c + i;
            const int wl = swz_slot(dl, pr >> 2) * 4 + (pr & 3);
            const int wh = swz_slot(dh, pr >> 2) * 4 + (pr & 3);
            Kb[buf][dl][wl] = cvt_pk_bf16(f0, f2);      // lo = even s
            Kb[buf][dh][wh] = cvt_pk_bf16(f1, f3);
            Vb[buf][dl][wl] = cvt_pk_bf16(b0[i], b2[i]);
            Vb[buf][dh][wh] = cvt_pk_bf16(b1[i], b3[i]);
        }

        __syncthreads();   // free drain: loads already consumed by the stores

        if (ch + 1 < NCHK_) {              // issue next chunk's loads NOW
            const size_t nb = rbase + (size_t)(ch + 1) * CHR_ * STRIDE_;
            kr0 = *(const float4*)(keys + nb);
            kr1 = *(const float4*)(keys + nb + 32);
            kr2 = *(const float4*)(keys + nb + STRIDE_);
            kr3 = *(const float4*)(keys + nb + STRIDE_ + 32);
            vr0 = *(const float4*)(values + nb);
            vr1 = *(const float4*)(values + nb + 32);
            vr2 = *(const float4*)(values + nb + STRIDE_);
            vr3 = *(const float4*)(values + nb + STRIDE_ + 32);
        }

        const int rk = 32 * wd + lm, rv = 32 * wm + lm;
        #pragma unroll
        for (int m = 0; m < 4; ++m) {
            const int sa = ((2 * m + lh) ^ (lm & 7) ^ (lm >> 2)) & 7;
            bf16x8 af = *(const bf16x8*)&Kb[buf][rk][sa * 4];
            bf16x8 bv = *(const bf16x8*)&Vb[buf][rv][sa * 4];
            acc = __builtin_amdgcn_mfma_f32_32x32x16_bf16(af, bv, acc, 0, 0, 0);
        }
    }

    // C/D layout (m74/m101): col=lane&31, row=(r&3)+8*(r>>2)+4*(lane>>5)
    float* dst = pkv + (size_t)blk * (E_ * E_);
    #pragma unroll
    for (int r = 0; r < 16; ++r) {
        const int ro = (r & 3) + 8 * (r >> 2) + 4 * lh;
        dst[(32 * wd + ro) * E_ + 32 * wm + lm] = acc[r];
    }

    // ksum: per-thread partials [8] -> LDS scratch (reuse Kb[0]) -> reduce
    __syncthreads();
    float* ksb = (float*)&Kb[0][0][0];     // [256][8] f32 = 8 KB
    *(float4*)&ksb[t * 8]     = make_float4(ksp[0], ksp[1], ksp[2], ksp[3]);
    *(float4*)&ksb[t * 8 + 4] = make_float4(ksp[4], ksp[5], ksp[6], ksp[7]);
    __syncthreads();
    if (t < E_) {
        const int cc = (t & 31) >> 2, e = (t >> 5) * 4 + (t & 3);
        float s = 0.f;
        #pragma unroll
        for (int pp = 0; pp < 32; ++pp) s += ksb[(pp * 8 + cc) * 8 + e];
        pks[(size_t)blk * E_ + t] = s;
    }
}

// ---------------------------------------------------------------------------
// Reduce: KV[d][m] = sum_c pkv; emit KV^T bf16 [m][d] + ksum f32.
// ---------------------------------------------------------------------------
__global__ __launch_bounds__(256) void la_reduce(
    const float* __restrict__ pkv, const float* __restrict__ pks,
    unsigned short* __restrict__ kvt, float* __restrict__ ksum)
{
    const int b = blockIdx.x, nh = b >> 4, sl = b & 15;
    const int e = sl * 256 + threadIdx.x;          // e = d*64 + m
    const float* src = pkv + (size_t)nh * SPLIT_ * (E_ * E_) + e;
    float s = 0.f;
    #pragma unroll
    for (int c = 0; c < SPLIT_; ++c) s += src[(size_t)c * (E_ * E_)];
    const int d = e >> 6, m = e & 63;
    kvt[(size_t)nh * (E_ * E_) + m * E_ + d] = f2bf(s);

    if (sl == 0 && threadIdx.x < E_) {
        const float* sp = pks + (size_t)nh * SPLIT_ * E_ + threadIdx.x;
        float ss = 0.f;
        #pragma unroll
        for (int c = 0; c < SPLIT_; ++c) ss += sp[c * E_];
        ksum[nh * E_ + threadIdx.x] = ss;
    }
}

// ---------------------------------------------------------------------------
// Phase 2: out[l][m] = z[l] * sum_d qf[l,d]*KV[d,m] via MFMA (r16 verbatim).
// Runs at the HBM roofline (134 MB roundtrip @ ~6.4 TB/s ~= 21 us).
// ---------------------------------------------------------------------------
__global__ __launch_bounds__(256) void la_out(
    const float* __restrict__ q, const unsigned short* __restrict__ kvt,
    const float* __restrict__ ksum, float* __restrict__ out)
{
    const int blk = blockIdx.x, nh = blk >> 5, tile = blk & 31;
    const int n = nh / H_, h = nh % H_;
    const int t = threadIdx.x, l = t & 63, w = t >> 6;
    const int lm = l & 31, lh = l >> 5;

    __shared__ float zbuf[4][32];

    const unsigned short* kb = kvt + (size_t)nh * (E_ * E_);
    const float* ks = ksum + nh * E_;

    bf16x8 bfr[4][2];
    float4 kr[4][2];
    #pragma unroll
    for (int st = 0; st < 4; ++st) {
        #pragma unroll
        for (int c = 0; c < 2; ++c)
            bfr[st][c] = *(const bf16x8*)&kb[(32 * c + lm) * E_ + st * 16 + 8 * lh];
        kr[st][0] = *(const float4*)&ks[st * 16 + 8 * lh];
        kr[st][1] = *(const float4*)&ks[st * 16 + 8 * lh + 4];
    }

    const size_t base = (size_t)n * (L_ * H_ * E_) + (size_t)h * E_;

    #pragma unroll
    for (int bnd = 0; bnd < 2; ++bnd) {
        const int l0 = tile * 256 + w * 64 + bnd * 32;
        const float* qp = q + base + (size_t)(l0 + lm) * STRIDE_ + 8 * lh;

        float4 qa[4], qb[4];
        #pragma unroll
        for (int st = 0; st < 4; ++st) {
            qa[st] = *(const float4*)(qp + st * 16);
            qb[st] = *(const float4*)(qp + st * 16 + 4);
        }

        float zd = 0.f;
        bf16x8 af[4];
        #pragma unroll
        for (int st = 0; st < 4; ++st) {
            const float f0 = featmap(qa[st].x), f1 = featmap(qa[st].y),
                        f2 = featmap(qa[st].z), f3 = featmap(qa[st].w);
            const float g0 = featmap(qb[st].x), g1 = featmap(qb[st].y),
                        g2 = featmap(qb[st].z), g3 = featmap(qb[st].w);
            zd += f0 * kr[st][0].x + f1 * kr[st][0].y + f2 * kr[st][0].z + f3 * kr[st][0].w
                + g0 * kr[st][1].x + g1 * kr[st][1].y + g2 * kr[st][1].z + g3 * kr[st][1].w;
            union { bf16x8 v; unsigned u[4]; } a;
            a.u[0] = cvt_pk_bf16(f0, f1);
            a.u[1] = cvt_pk_bf16(f2, f3);
            a.u[2] = cvt_pk_bf16(g0, g1);
            a.u[3] = cvt_pk_bf16(g2, g3);
            af[st] = a.v;
        }
        zd += __shfl_xor(zd, 32);
        const float z = 1.0f / (zd + 1e-6f);
        if (l < 32) zbuf[w][l] = z;
        __builtin_amdgcn_wave_barrier();

        f32x16 c0 = {0,0,0,0,0,0,0,0,0,0,0,0,0,0,0,0};
        f32x16 c1 = {0,0,0,0,0,0,0,0,0,0,0,0,0,0,0,0};
        #pragma unroll
        for (int st = 0; st < 4; ++st) {
            c0 = __builtin_amdgcn_mfma_f32_32x32x16_bf16(af[st], bfr[st][0], c0, 0, 0, 0);
            c1 = __builtin_amdgcn_mfma_f32_32x32x16_bf16(af[st], bfr[st][1], c1, 0, 0, 0);
        }

        float* op = out + base + (size_t)l0 * STRIDE_ + lm;
        #pragma unroll
        for (int r = 0; r < 16; ++r) {
            const int ro = (r & 3) + 8 * (r >> 2) + 4 * lh;
            const float zz = zbuf[w][ro];
            op[(size_t)ro * STRIDE_]      = c0[r] * zz;
            op[(size_t)ro * STRIDE_ + 32] = c1[r] * zz;
        }
        __builtin_amdgcn_wave_barrier();   // zbuf reused next band
    }
}

// ws layout (floats): pkv[NH*SPLIT][4096] | pks[NH*SPLIT][64] |
//                     kvt bf16 (float-sized area) | ksum[NH][64]
extern "C" void kernel_launch(void* const* d_in, const int* in_sizes, int n_in,
                              void* d_out, int out_size, void* d_ws, size_t ws_size,
                              hipStream_t stream) {
    (void)in_sizes; (void)n_in; (void)out_size; (void)ws_size;
    const float* qq = (const float*)d_in[0];
    const float* kk = (const float*)d_in[1];
    const float* vv = (const float*)d_in[2];
    float* outp = (float*)d_out;
    float* ws   = (float*)d_ws;

    float* pkv = ws;
    float* pks = ws + (size_t)NH_ * SPLIT_ * (E_ * E_);
    unsigned short* kvt = (unsigned short*)(pks + (size_t)NH_ * SPLIT_ * E_);
    float* ksm = (float*)(kvt + (size_t)NH_ * (E_ * E_));

    la_kv<<<NH_ * SPLIT_, 256, 0, stream>>>(kk, vv, pkv, pks);
    la_reduce<<<NH_ * 16, 256, 0, stream>>>(pkv, pks, kvt, ksm);
    la_out<<<NH_ * 32, 256, 0, stream>>>(qq, kvt, ksm, outp);
}